// Round 1
// 217.565 us; speedup vs baseline: 1.0029x; 1.0029x over previous
//
#include <hip/hip_runtime.h>

#define NT 512     // trajectories
#define PD 256     // dimension

__device__ __forceinline__ float wave_reduce_sum(float v) {
    #pragma unroll
    for (int m = 32; m >= 1; m >>= 1) v += __shfl_xor(v, m, 64);
    return v;
}

// One block per trajectory. Phase 1: dual matvec vs predicted_mat with DIRECT
// coalesced global->register reads (no LDS transpose): 16 lanes per row, lane
// owns cols 4*(l&15)+64*j, x-vectors register-resident, 4-level shfl_xor
// butterfly finishes each row. 2-deep prefetch pipeline. Phase 2: tiny-MLP
// epilogue + rank-2 BFGS update applied directly to v = -grad (unchanged,
// validated in earlier rounds).
__global__ __launch_bounds__(256, 4) void fused_kernel(
    const float* __restrict__ pm, const float* __restrict__ grad,
    const float* __restrict__ gradm1, const float* __restrict__ dm1,
    const float* __restrict__ Wfs, const float* __restrict__ Wo1,
    const float* __restrict__ Wo2, const float* __restrict__ Wo3,
    const float* __restrict__ Wl1, const float* __restrict__ Wl2,
    const float* __restrict__ Wl3, float* __restrict__ dout)
{
    __shared__ __align__(16) float sdg[PD];   // grad - gradm1
    __shared__ __align__(16) float sgv[PD];   // grad
    __shared__ float qres[PD];                // pm @ (grad-gradm1)
    __shared__ float pgres[PD];               // pm @ grad
    __shared__ float sW[516];
    __shared__ float redA[4][3];
    __shared__ float redB[4][4];

    const int t    = threadIdx.x;
    const int lane = t & 63;
    const int wave = t >> 6;
    const int n    = blockIdx.x;
    const int l15  = lane & 15;   // column-chunk owner within row
    const int l4   = lane >> 4;   // row-within-group (0..3)

    // ---- stage tiny weights (consumed after the phase-1 barrier) ----
    if (t < 18) sW[t]       = Wo1[t];
    if (t < 72) sW[18 + t]  = Wo2[t];
    if (t < 36) sW[90 + t]  = Wo3[t];
    if (t < 72) sW[126 + t] = Wl1[t];
    sW[198 + t] = Wl2[t];
    if (t < 32) sW[198 + 256 + t] = Wl2[256 + t];
    if (t < 24) sW[486 + t] = Wl3[t];
    if (t < 6)  sW[510 + t] = Wfs[t];

    // ---- stage x-vectors in LDS, keep own elements in regs for epilogue ----
    const int idx = n * PD + t;
    const float g_t  = grad[idx];
    const float gm_t = gradm1[idx];
    const float dm_t = dm1[idx];
    sdg[t] = g_t - gm_t;
    sgv[t] = g_t;
    __syncthreads();

    // lane's 16 columns: 4*(l15) + 64*j + i  (j=0..3, i=0..3)
    float dgv[16], gvv[16];
    #pragma unroll
    for (int j = 0; j < 4; ++j) {
        const float4 a = ((const float4*)(sdg + 64 * j))[l15];
        const float4 b = ((const float4*)(sgv + 64 * j))[l15];
        dgv[4*j+0] = a.x; dgv[4*j+1] = a.y; dgv[4*j+2] = a.z; dgv[4*j+3] = a.w;
        gvv[4*j+0] = b.x; gvv[4*j+1] = b.y; gvv[4*j+2] = b.z; gvv[4*j+3] = b.w;
    }

    // ---- phase 1: wave w owns rows [64w, 64w+64), 4 rows per iteration ----
    const float* rb = pm + (size_t)n * PD * PD
                    + (size_t)(64 * wave + l4) * PD + 4 * l15;

    float4 cur[4], nxt[4];
    #pragma unroll
    for (int j = 0; j < 4; ++j) cur[j] = *(const float4*)(rb + 64 * j);

    #pragma unroll 1
    for (int it = 0; it < 16; ++it) {
        if (it < 15) {   // uniform branch: prefetch next 4-row group
            const float* rb2 = rb + (size_t)(it + 1) * 4 * PD;
            #pragma unroll
            for (int j = 0; j < 4; ++j) nxt[j] = *(const float4*)(rb2 + 64 * j);
        }
        float sq = 0.f, sg = 0.f;
        #pragma unroll
        for (int j = 0; j < 4; ++j) {
            sq += cur[j].x * dgv[4*j+0]; sg += cur[j].x * gvv[4*j+0];
            sq += cur[j].y * dgv[4*j+1]; sg += cur[j].y * gvv[4*j+1];
            sq += cur[j].z * dgv[4*j+2]; sg += cur[j].z * gvv[4*j+2];
            sq += cur[j].w * dgv[4*j+3]; sg += cur[j].w * gvv[4*j+3];
        }
        // 16-lane butterfly: sum across the row's 16 column owners
        #pragma unroll
        for (int m = 1; m <= 8; m <<= 1) {
            sq += __shfl_xor(sq, m, 64);
            sg += __shfl_xor(sg, m, 64);
        }
        if (l15 == 0) {
            const int row = 64 * wave + 4 * it + l4;
            qres[row]  = sq;
            pgres[row] = sg;
        }
        #pragma unroll
        for (int j = 0; j < 4; ++j) cur[j] = nxt[j];
    }
    __syncthreads();

    // ---- phase 2: epilogue (validated) ----
    const float q  = qres[t];
    const float pg = pgres[t];
    const float bg = -pg;              // Bg = -pm@grad = pm@v
    const float dm = dm_t;

    const float x0 = q, x1 = dm, x2 = bg;

    // outer_FF: 3 -> 6 -> 12 -> 3
    float h1[6];
    #pragma unroll
    for (int j = 0; j < 6; ++j) {
        float s = sW[j*3] * x0 + sW[j*3 + 1] * x1 + sW[j*3 + 2] * x2;
        h1[j] = fmaxf(s, 0.f);
    }
    float h2[12];
    #pragma unroll
    for (int j = 0; j < 12; ++j) {
        float s = 0.f;
        #pragma unroll
        for (int i = 0; i < 6; ++i) s += sW[18 + j*6 + i] * h1[i];
        h2[j] = fmaxf(s, 0.f);
    }
    float o0 = 0.f, o1 = 0.f, o2 = 0.f;
    #pragma unroll
    for (int i = 0; i < 12; ++i) {
        o0 += sW[90 + i]      * h2[i];
        o1 += sW[90 + 12 + i] * h2[i];
        o2 += sW[90 + 24 + i] * h2[i];
    }

    // mean over P (block reduction)
    float r0 = wave_reduce_sum(o0);
    float r1 = wave_reduce_sum(o1);
    float r2 = wave_reduce_sum(o2);
    if (lane == 0) { redA[wave][0] = r0; redA[wave][1] = r1; redA[wave][2] = r2; }
    __syncthreads();
    const float inv = 1.0f / 256.0f;
    const float of0 = (redA[0][0] + redA[1][0] + redA[2][0] + redA[3][0]) * inv;
    const float of1 = (redA[0][1] + redA[1][1] + redA[2][1] + redA[3][1]) * inv;
    const float of2 = (redA[0][2] + redA[1][2] + redA[2][2] + redA[3][2]) * inv;

    const float x6[6] = {x0, x1, x2, of0, of1, of2};

    float fullskip = 0.f;
    #pragma unroll
    for (int i = 0; i < 6; ++i) fullskip += sW[510 + i] * x6[i];

    // inner MLP: 6 -> 12 -> 24 -> 1
    float l1[12];
    #pragma unroll
    for (int j = 0; j < 12; ++j) {
        float s = 0.f;
        #pragma unroll
        for (int i = 0; i < 6; ++i) s += sW[126 + j*6 + i] * x6[i];
        l1[j] = fmaxf(s, 0.f);
    }
    float l2[24];
    #pragma unroll
    for (int j = 0; j < 24; ++j) {
        float s = 0.f;
        #pragma unroll
        for (int i = 0; i < 12; ++i) s += sW[198 + j*12 + i] * l1[i];
        l2[j] = fmaxf(s, 0.f);
    }
    float out = fullskip;
    #pragma unroll
    for (int i = 0; i < 24; ++i) out += sW[486 + i] * l2[i];

    const float dgk    = g_t - gm_t;
    const float secant = dm - q;

    // four simultaneous block reductions
    float pd  = wave_reduce_sum(out * dgk);
    float ps  = wave_reduce_sum(secant * dgk);
    float po  = wave_reduce_sum(out * g_t);
    float psg = wave_reduce_sum(secant * g_t);
    if (lane == 0) {
        redB[wave][0] = pd; redB[wave][1] = ps;
        redB[wave][2] = po; redB[wave][3] = psg;
    }
    __syncthreads();
    const float denom = redB[0][0] + redB[1][0] + redB[2][0] + redB[3][0];
    const float sdgk  = redB[0][1] + redB[1][1] + redB[2][1] + redB[3][1];
    const float og    = redB[0][2] + redB[1][2] + redB[2][2] + redB[3][2];
    const float sg2   = redB[0][3] + redB[1][3] + redB[2][3] + redB[3][3];

    // d = Bg + (1/denom)*( secant*(out.v) + out*(secant.v) - coef*out*(out.v) ),
    // v = -grad => out.v = -og, secant.v = -sg2, coef = sdgk/denom
    const float invd = 1.0f / denom;
    const float coef = sdgk * invd;
    const float d = bg + (-secant * og - out * sg2 + coef * out * og) * invd;
    dout[idx] = d;
}

extern "C" void kernel_launch(void* const* d_in, const int* in_sizes, int n_in,
                              void* d_out, int out_size, void* d_ws, size_t ws_size,
                              hipStream_t stream) {
    const float* grad   = (const float*)d_in[0];
    const float* gradm1 = (const float*)d_in[1];
    const float* dm1    = (const float*)d_in[2];
    const float* pm     = (const float*)d_in[3];
    const float* Wfs    = (const float*)d_in[4];
    const float* Wo1    = (const float*)d_in[5];
    const float* Wo2    = (const float*)d_in[6];
    const float* Wo3    = (const float*)d_in[7];
    const float* Wl1    = (const float*)d_in[8];
    const float* Wl2    = (const float*)d_in[9];
    const float* Wl3    = (const float*)d_in[10];

    fused_kernel<<<NT, 256, 0, stream>>>(pm, grad, gradm1, dm1,
                                         Wfs, Wo1, Wo2, Wo3, Wl1, Wl2, Wl3,
                                         (float*)d_out);
}